// Round 9
// baseline (89.186 us; speedup 1.0000x reference)
//
#include <hip/hip_runtime.h>

typedef float vfloat4 __attribute__((ext_vector_type(4)));

#define B_ROWS 128
#define T_SAMP 160000
#define NSEC 3
#define LCH 20     // samples per chunk (one lane)
#define NF4 5      // float4 loads per lane
#define RST 21     // LDS transpose row stride (odd -> free 2-way banks)
#define SUPW 1280  // samples per superchunk (64 lanes * 20)
#define NSUP 125   // superchunks per row
#define NWAVE 16   // waves per block (1024 threads)
#define NIT 8      // ceil(125/16)

struct Coefs { float b0[NSEC], b1[NSEC], b2[NSEC], a1[NSEC], a2[NSEC]; };

__device__ __forceinline__ void load_coefs(const float* __restrict__ sos, Coefs& c) {
#pragma unroll
  for (int s = 0; s < NSEC; ++s) {
    c.b0[s] = sos[s * 6 + 0];
    c.b1[s] = sos[s * 6 + 1];
    c.b2[s] = sos[s * 6 + 2];
    c.a1[s] = sos[s * 6 + 4];
    c.a2[s] = sos[s * 6 + 5];
  }
}

// One DF2T cascade time-step, same op order as the reference.
__device__ __forceinline__ float df2t_step(const Coefs& c, float z[6], float x) {
  float y = x;
#pragma unroll
  for (int s = 0; s < NSEC; ++s) {
    float out = fmaf(c.b0[s], y, z[2 * s]);
    float t0  = fmaf(c.b1[s], y, z[2 * s + 1]);
    z[2 * s]     = fmaf(-c.a1[s], out, t0);
    float t1  = c.b2[s] * y;
    z[2 * s + 1] = fmaf(-c.a2[s], out, t1);
    y = out;
  }
  return y;
}

// Affine combine f := f + P*t; cascade matrices are 2x2-block lower-triangular.
__device__ __forceinline__ void tri_combine(float f[6], const float* __restrict__ P,
                                            const float t[6]) {
  float nf[6];
#pragma unroll
  for (int e = 0; e < 6; ++e) {
    float acc = f[e];
    const int kmax = ((e >> 1) << 1) + 2;
#pragma unroll
    for (int kk = 0; kk < 6; ++kk)
      if (kk < kmax) acc = fmaf(P[e * 6 + kk], t[kk], acc);
    nf[e] = acc;
  }
#pragma unroll
  for (int e = 0; e < 6; ++e) f[e] = nf[e];
}

// Lane-distributed 6x6 matmul: lane e<36 holds element (e/6, e%6).
__device__ __forceinline__ float dmm6(float a, float b, int i, int j) {
  float s = 0.f;
#pragma unroll
  for (int k = 0; k < 6; ++k)
    s = fmaf(__shfl(a, i * 6 + k), __shfl(b, k * 6 + j), s);
  return s;
}

__global__ __launch_bounds__(1024) void row_kernel(const float* __restrict__ x,
                                                   const float* __restrict__ sos,
                                                   float* __restrict__ y) {
  __shared__ float Ash[36];       // A, bounced via LDS (avoids runtime-idx scratch)
  __shared__ float As5[5 * 36];   // A^(2^k), k=0..4 (g-table)
  __shared__ float Pm[6 * 36];    // P_k = M^(2^k), M = A^20 (wave scan)
  __shared__ float Qm[4 * 36];    // Q^(2^k), Q = M^64 (cross-wave scan)
  __shared__ float Gm[LCH * 6];   // g_t = c^T A^t
  __shared__ float Fw[NWAVE * 6]; // per-wave zero-state aggregates
  __shared__ float Zw[NWAVE * 6]; // per-wave start states
  __shared__ float Zc[6];         // row carry state
  __shared__ float Tr[NWAVE][64 * RST];

  const int tid = threadIdx.x;
  const int w = tid >> 6, lane = tid & 63;
  const int r = blockIdx.x;
  Coefs cf; load_coefs(sos, cf);

  // thread 0: build A (all indices compile-time -> registers), store to LDS
  if (tid == 0) {
    float A[36];
#pragma unroll
    for (int jc = 0; jc < 6; ++jc) {
      float z[6] = {0.f, 0.f, 0.f, 0.f, 0.f, 0.f};
      z[jc] = 1.f;
      df2t_step(cf, z, 0.f);
#pragma unroll
      for (int ic = 0; ic < 6; ++ic) A[ic * 6 + jc] = z[ic];
    }
#pragma unroll
    for (int q = 0; q < 36; ++q) Ash[q] = A[q];
#pragma unroll
    for (int e = 0; e < 6; ++e) Zc[e] = 0.f;
  }
  __syncthreads();  // Ash ready

  const float* xrow = x + (size_t)r * T_SAMP;
  float* yrow = y + (size_t)r * T_SAMP;

  // preload iter 0 (overlaps matrix build)
  {
    const float4* s0p = reinterpret_cast<const float4*>(xrow + (size_t)w * SUPW + lane * LCH);
    // loads issued below via v init
  }
  const float4* src0 = reinterpret_cast<const float4*>(xrow + (size_t)w * SUPW + lane * LCH);
  float4 v0 = src0[0], v1 = src0[1], v2 = src0[2], v3 = src0[3], v4 = src0[4];

  if (w == 0) {  // wave 0 builds all matrices (distributed over lanes via LDS read)
    const int e = (lane < 36) ? lane : 0;
    const int mi = e / 6, mj = e % 6;
    float a1p = Ash[e];
    float a2p = dmm6(a1p, a1p, mi, mj);
    float a4p = dmm6(a2p, a2p, mi, mj);
    float a8p = dmm6(a4p, a4p, mi, mj);
    float a16p = dmm6(a8p, a8p, mi, mj);
    if (lane < 36) {
      As5[lane] = a1p; As5[36 + lane] = a2p; As5[72 + lane] = a4p;
      As5[108 + lane] = a8p; As5[144 + lane] = a16p;
    }
    float pk = dmm6(a16p, a4p, mi, mj);  // M = A^20
    if (lane < 36) Pm[lane] = pk;
#pragma unroll
    for (int k = 1; k < 6; ++k) {
      pk = dmm6(pk, pk, mi, mj);
      if (lane < 36) Pm[k * 36 + lane] = pk;
    }
    float q = dmm6(pk, pk, mi, mj);      // Q = M^64
    if (lane < 36) Qm[lane] = q;
#pragma unroll
    for (int k = 1; k < 4; ++k) {
      q = dmm6(q, q, mi, mj);
      if (lane < 36) Qm[k * 36 + lane] = q;
    }
    // g-table: g_t = c^T A^t, c = [b0_1*b0_2, 0, b0_2, 0, 1, 0]
    // (reads As5 written by this same wave: in-order LDS, no barrier needed)
    if (lane < LCH) {
      float g[6] = {cf.b0[1] * cf.b0[2], 0.f, cf.b0[2], 0.f, 1.f, 0.f};
#pragma unroll
      for (int k = 0; k < 5; ++k) {
        if (lane & (1 << k)) {
          float ng[6];
#pragma unroll
          for (int j = 0; j < 6; ++j) {
            float acc = 0.f;
#pragma unroll
            for (int i = 0; i < 6; ++i) acc = fmaf(g[i], As5[k * 36 + i * 6 + j], acc);
            ng[j] = acc;
          }
#pragma unroll
          for (int j = 0; j < 6; ++j) g[j] = ng[j];
        }
      }
#pragma unroll
      for (int j = 0; j < 6; ++j) Gm[lane * 6 + j] = g[j];
    }
  }
  __syncthreads();  // matrices ready

  for (int it = 0; it < NIT; ++it) {
    const int s = it * NWAVE + w;
    const bool active = (s < NSUP);

    // zero-state pass capturing y_zero in-place; f = chunk zero-state final
    float f[6] = {0.f, 0.f, 0.f, 0.f, 0.f, 0.f};
    v0.x = df2t_step(cf, f, v0.x); v0.y = df2t_step(cf, f, v0.y);
    v0.z = df2t_step(cf, f, v0.z); v0.w = df2t_step(cf, f, v0.w);
    v1.x = df2t_step(cf, f, v1.x); v1.y = df2t_step(cf, f, v1.y);
    v1.z = df2t_step(cf, f, v1.z); v1.w = df2t_step(cf, f, v1.w);
    v2.x = df2t_step(cf, f, v2.x); v2.y = df2t_step(cf, f, v2.y);
    v2.z = df2t_step(cf, f, v2.z); v2.w = df2t_step(cf, f, v2.w);
    v3.x = df2t_step(cf, f, v3.x); v3.y = df2t_step(cf, f, v3.y);
    v3.z = df2t_step(cf, f, v3.z); v3.w = df2t_step(cf, f, v3.w);
    v4.x = df2t_step(cf, f, v4.x); v4.y = df2t_step(cf, f, v4.y);
    v4.z = df2t_step(cf, f, v4.z); v4.w = df2t_step(cf, f, v4.w);

    // prefetch next iteration (clamped); latency hides under scan/correction
    float4 n0, n1, n2, n3, n4;
    if (it + 1 < NIT) {
      int sn = (it + 1) * NWAVE + w;
      if (sn > NSUP - 1) sn = NSUP - 1;
      const float4* srcn = reinterpret_cast<const float4*>(xrow + (size_t)sn * SUPW + lane * LCH);
      n0 = srcn[0]; n1 = srcn[1]; n2 = srcn[2]; n3 = srcn[3]; n4 = srcn[4];
    }

    // wave scan of per-chunk aggregates
#pragma unroll
    for (int k = 0; k < 6; ++k) {
      float t6[6];
#pragma unroll
      for (int e = 0; e < 6; ++e) t6[e] = __shfl_up(f[e], 1 << k);
      if (lane >= (1 << k)) tri_combine(f, Pm + k * 36, t6);
    }
    float excl[6];
#pragma unroll
    for (int e = 0; e < 6; ++e) {
      float tt = __shfl_up(f[e], 1);
      excl[e] = (lane == 0) ? 0.f : tt;
    }
    if (lane == 63) {
#pragma unroll
      for (int e = 0; e < 6; ++e) Fw[w * 6 + e] = f[e];
    }
    __syncthreads();  // b1: Fw ready

    // wave 0: cross-wave affine scan over 16 superchunk aggregates
    if (w == 0) {
      const int l = lane & 15;
      float F[6];
#pragma unroll
      for (int e = 0; e < 6; ++e) F[e] = Fw[l * 6 + e];
      float zc[6];
#pragma unroll
      for (int e = 0; e < 6; ++e) zc[e] = Zc[e];
      if (lane == 0) tri_combine(F, Qm, zc);  // fold carry: F0 += Q*zc
#pragma unroll
      for (int k = 0; k < 4; ++k) {
        float t6[6];
#pragma unroll
        for (int e = 0; e < 6; ++e) t6[e] = __shfl_up(F[e], 1 << k);
        if (lane < 16 && lane >= (1 << k)) tri_combine(F, Qm + k * 36, t6);
      }
      float zst[6];
#pragma unroll
      for (int e = 0; e < 6; ++e) {
        float tt = __shfl_up(F[e], 1);
        zst[e] = (lane == 0) ? zc[e] : tt;
      }
      if (lane < 16) {
#pragma unroll
        for (int e = 0; e < 6; ++e) Zw[lane * 6 + e] = zst[e];
      }
      if (lane == 15) {
#pragma unroll
        for (int e = 0; e < 6; ++e) Zc[e] = F[e];  // new carry
      }
    }
    __syncthreads();  // b2: Zw ready

    // zs = excl + M^lane * z0 (binary decomposition via Pm)
    float z0[6];
#pragma unroll
    for (int e = 0; e < 6; ++e) z0[e] = Zw[w * 6 + e];
    float wv[6];
#pragma unroll
    for (int e = 0; e < 6; ++e) wv[e] = z0[e];
#pragma unroll
    for (int k = 0; k < 6; ++k) {
      if ((lane >> k) & 1) {
        float nw[6];
#pragma unroll
        for (int e = 0; e < 6; ++e) {
          float a = 0.f;
          const int kmax = ((e >> 1) << 1) + 2;
#pragma unroll
          for (int kk = 0; kk < 6; ++kk)
            if (kk < kmax) a = fmaf(Pm[k * 36 + e * 6 + kk], wv[kk], a);
          nw[e] = a;
        }
#pragma unroll
        for (int e = 0; e < 6; ++e) wv[e] = nw[e];
      }
    }
    float zs[6];
#pragma unroll
    for (int e = 0; e < 6; ++e) zs[e] = excl[e] + wv[e];

    // linear correction y = y_zero + g_t . zs -> LDS transpose rows
    float* myrow = &Tr[w][lane * RST];
    auto corr = [&](int tl, float yz) {
      float a = yz;
#pragma unroll
      for (int e = 0; e < 6; ++e) a = fmaf(Gm[tl * 6 + e], zs[e], a);
      myrow[tl] = a;
    };
    corr(0, v0.x);  corr(1, v0.y);  corr(2, v0.z);  corr(3, v0.w);
    corr(4, v1.x);  corr(5, v1.y);  corr(6, v1.z);  corr(7, v1.w);
    corr(8, v2.x);  corr(9, v2.y);  corr(10, v2.z); corr(11, v2.w);
    corr(12, v3.x); corr(13, v3.y); corr(14, v3.z); corr(15, v3.w);
    corr(16, v4.x); corr(17, v4.y); corr(18, v4.z); corr(19, v4.w);
    __syncthreads();  // b3: transpose buffers ready

    if (active) {
      float* dst = yrow + (size_t)s * SUPW;
#pragma unroll
      for (int i2 = 0; i2 < NF4; ++i2) {
        int q = i2 * 64 + lane, k = q / NF4, m = q - k * NF4;
        vfloat4 w4;
        w4.x = Tr[w][k * RST + m * 4 + 0];
        w4.y = Tr[w][k * RST + m * 4 + 1];
        w4.z = Tr[w][k * RST + m * 4 + 2];
        w4.w = Tr[w][k * RST + m * 4 + 3];
        __builtin_nontemporal_store(w4, reinterpret_cast<vfloat4*>(dst + 4 * q));
      }
    }
    v0 = n0; v1 = n1; v2 = n2; v3 = n3; v4 = n4;
  }
}

extern "C" void kernel_launch(void* const* d_in, const int* in_sizes, int n_in,
                              void* d_out, int out_size, void* d_ws, size_t ws_size,
                              hipStream_t stream) {
  const float* x = (const float*)d_in[0];
  const float* sos = (const float*)d_in[1];
  float* y = (float*)d_out;
  hipLaunchKernelGGL(row_kernel, dim3(B_ROWS), dim3(1024), 0, stream, x, sos, y);
}

// Round 10
// 63.276 us; speedup vs baseline: 1.4095x; 1.4095x over previous
//
#include <hip/hip_runtime.h>

typedef float vfloat4 __attribute__((ext_vector_type(4)));

#define B_ROWS 128
#define T_SAMP 160000
#define NSEC 3
#define LCH 20     // samples per chunk (one lane)
#define NF4 5      // float4 loads per lane
#define RST 21     // LDS transpose row stride (odd -> free 2-way banks)
#define SUPW 1280  // samples per superchunk (64 lanes * 20)
#define NSUP 125   // superchunks per row
#define NSC (B_ROWS * NSUP)  // 16000
#define WPB 4
// mats layout in workspace: [0..215]   Pm: P_k = M^(2^k), M = A^20, k=0..5
//                           [216..467] Qm: Q_k = (M^64)^(2^k), k=0..6

struct Coefs { float b0[NSEC], b1[NSEC], b2[NSEC], a1[NSEC], a2[NSEC]; };

__device__ __forceinline__ void load_coefs(const float* __restrict__ sos, Coefs& c) {
#pragma unroll
  for (int s = 0; s < NSEC; ++s) {
    c.b0[s] = sos[s * 6 + 0];
    c.b1[s] = sos[s * 6 + 1];
    c.b2[s] = sos[s * 6 + 2];
    c.a1[s] = sos[s * 6 + 4];
    c.a2[s] = sos[s * 6 + 5];
  }
}

// One DF2T cascade time-step, same op order as the reference.
__device__ __forceinline__ float df2t_step(const Coefs& c, float z[6], float x) {
  float y = x;
#pragma unroll
  for (int s = 0; s < NSEC; ++s) {
    float out = fmaf(c.b0[s], y, z[2 * s]);
    float t0  = fmaf(c.b1[s], y, z[2 * s + 1]);
    z[2 * s]     = fmaf(-c.a1[s], out, t0);
    float t1  = c.b2[s] * y;
    z[2 * s + 1] = fmaf(-c.a2[s], out, t1);
    y = out;
  }
  return y;
}

// Affine combine f := f + P*t; cascade matrices are 2x2-block lower-triangular.
// P points at GLOBAL mats (uniform address, compile-time offsets -> s_load).
__device__ __forceinline__ void tri_combine(float f[6], const float* __restrict__ P,
                                            const float t[6]) {
  float nf[6];
#pragma unroll
  for (int e = 0; e < 6; ++e) {
    float acc = f[e];
    const int kmax = ((e >> 1) << 1) + 2;
#pragma unroll
    for (int kk = 0; kk < 6; ++kk)
      if (kk < kmax) acc = fmaf(P[e * 6 + kk], t[kk], acc);
    nf[e] = acc;
  }
#pragma unroll
  for (int e = 0; e < 6; ++e) f[e] = nf[e];
}

// Lane-distributed 6x6 matmul: lane e<36 holds element (e/6, e%6).
__device__ __forceinline__ float dmm6(float a, float b, int i, int j) {
  float s = 0.f;
#pragma unroll
  for (int k = 0; k < 6; ++k)
    s = fmaf(__shfl(a, i * 6 + k), __shfl(b, k * 6 + j), s);
  return s;
}

// Setup: one wave computes all transition-matrix powers -> mats (global ws).
__global__ __launch_bounds__(64) void setup_kernel(const float* __restrict__ sos,
                                                   float* __restrict__ mats) {
  __shared__ float Ash[36];
  const int lane = threadIdx.x;
  Coefs cf; load_coefs(sos, cf);
  if (lane == 0) {  // build A with compile-time indices only (rule #20)
    float A[36];
#pragma unroll
    for (int jc = 0; jc < 6; ++jc) {
      float z[6] = {0.f, 0.f, 0.f, 0.f, 0.f, 0.f};
      z[jc] = 1.f;
      df2t_step(cf, z, 0.f);
#pragma unroll
      for (int ic = 0; ic < 6; ++ic) A[ic * 6 + jc] = z[ic];
    }
#pragma unroll
    for (int q = 0; q < 36; ++q) Ash[q] = A[q];
  }
  __syncthreads();

  const int e = (lane < 36) ? lane : 0;
  const int mi = e / 6, mj = e % 6;
  float a1p = Ash[e];
  float a2p  = dmm6(a1p, a1p, mi, mj);
  float a4p  = dmm6(a2p, a2p, mi, mj);
  float a8p  = dmm6(a4p, a4p, mi, mj);
  float a16p = dmm6(a8p, a8p, mi, mj);
  float pk = dmm6(a16p, a4p, mi, mj);  // M = A^20
  if (lane < 36) mats[lane] = pk;
#pragma unroll
  for (int k = 1; k < 6; ++k) {
    pk = dmm6(pk, pk, mi, mj);
    if (lane < 36) mats[k * 36 + lane] = pk;
  }
  float q = dmm6(pk, pk, mi, mj);      // Q = M^64
  if (lane < 36) mats[216 + lane] = q;
#pragma unroll
  for (int k = 1; k < 7; ++k) {
    q = dmm6(q, q, mi, mj);
    if (lane < 36) mats[216 + k * 36 + lane] = q;
  }
}

// Pass 1: register-direct, ZERO LDS. Zero-state final per chunk, wave scan,
// lane 63 writes superchunk aggregate.
__global__ __launch_bounds__(256) void pass1_kernel(const float* __restrict__ x,
                                                    const float* __restrict__ sos,
                                                    const float* __restrict__ mats,
                                                    float* __restrict__ Fsup) {
  const int tid = threadIdx.x, w = tid >> 6, lane = tid & 63;
  Coefs cf; load_coefs(sos, cf);
  const int S = blockIdx.x * WPB + w;
  const int r = S / NSUP, s = S - r * NSUP;
  const float4* src = reinterpret_cast<const float4*>(
      x + (size_t)r * T_SAMP + (size_t)s * SUPW + (size_t)lane * LCH);
  float4 v0 = src[0], v1 = src[1], v2 = src[2], v3 = src[3], v4 = src[4];

  float f[6] = {0.f, 0.f, 0.f, 0.f, 0.f, 0.f};
  df2t_step(cf, f, v0.x); df2t_step(cf, f, v0.y); df2t_step(cf, f, v0.z); df2t_step(cf, f, v0.w);
  df2t_step(cf, f, v1.x); df2t_step(cf, f, v1.y); df2t_step(cf, f, v1.z); df2t_step(cf, f, v1.w);
  df2t_step(cf, f, v2.x); df2t_step(cf, f, v2.y); df2t_step(cf, f, v2.z); df2t_step(cf, f, v2.w);
  df2t_step(cf, f, v3.x); df2t_step(cf, f, v3.y); df2t_step(cf, f, v3.z); df2t_step(cf, f, v3.w);
  df2t_step(cf, f, v4.x); df2t_step(cf, f, v4.y); df2t_step(cf, f, v4.z); df2t_step(cf, f, v4.w);

#pragma unroll
  for (int k = 0; k < 6; ++k) {
    float t6[6];
#pragma unroll
    for (int e = 0; e < 6; ++e) t6[e] = __shfl_up(f[e], 1 << k);
    if (lane >= (1 << k)) tri_combine(f, mats + k * 36, t6);
  }
  if (lane == 63) {
    float* fo = Fsup + (size_t)S * 6;
#pragma unroll
    for (int e = 0; e < 6; ++e) fo[e] = f[e];
  }
}

// Middle: per-row scan over NSUP superchunks: z[s+1] = Q z[s] + Fsup[s].
__global__ __launch_bounds__(64) void middle_scan(const float* __restrict__ Fsup,
                                                  const float* __restrict__ mats,
                                                  float* __restrict__ zsup) {
  const float* Qm = mats + 216;
  const int r = blockIdx.x, lane = threadIdx.x;
  const float* frow = Fsup + (size_t)r * NSUP * 6;
  float fc[2][6];
#pragma unroll
  for (int jj = 0; jj < 2; ++jj) {
    int c = 2 * lane + jj;
#pragma unroll
    for (int e = 0; e < 6; ++e) fc[jj][e] = (c < NSUP) ? frow[c * 6 + e] : 0.f;
  }
  float s[6] = {0.f, 0.f, 0.f, 0.f, 0.f, 0.f};
#pragma unroll
  for (int jj = 0; jj < 2; ++jj) {
    float ns[6];
#pragma unroll
    for (int e = 0; e < 6; ++e) {
      float acc = fc[jj][e];
#pragma unroll
      for (int kk = 0; kk < 6; ++kk) acc = fmaf(Qm[e * 6 + kk], s[kk], acc);
      ns[e] = acc;
    }
#pragma unroll
    for (int e = 0; e < 6; ++e) s[e] = ns[e];
  }
#pragma unroll
  for (int k = 0; k < 6; ++k) {
    float t[6];
#pragma unroll
    for (int e = 0; e < 6; ++e) t[e] = __shfl_up(s[e], 1 << k);
    if (lane >= (1 << k)) tri_combine(s, Qm + (k + 1) * 36, t);
  }
  float z[6];
#pragma unroll
  for (int e = 0; e < 6; ++e) {
    float t = __shfl_up(s[e], 1);
    z[e] = (lane == 0) ? 0.f : t;
  }
  float* zrow = zsup + (size_t)r * NSUP * 6;
#pragma unroll
  for (int jj = 0; jj < 2; ++jj) {
    int c = 2 * lane + jj;
    if (c < NSUP) {
#pragma unroll
      for (int e = 0; e < 6; ++e) zrow[c * 6 + e] = z[e];
    }
    float nz[6];
#pragma unroll
    for (int e = 0; e < 6; ++e) {
      float acc = fc[jj][e];
#pragma unroll
      for (int kk = 0; kk < 6; ++kk) acc = fmaf(Qm[e * 6 + kk], z[kk], acc);
      nz[e] = acc;
    }
#pragma unroll
    for (int e = 0; e < 6; ++e) z[e] = nz[e];
  }
}

// Pass 2: zero-state pass (keeps v intact) -> scan WITH z0 folded at lane 0
// (excl output IS the chunk-start state) -> true filter from zs -> LDS
// transpose -> dense nontemporal stores. LDS = transpose buffer only.
__global__ __launch_bounds__(256) void pass2_kernel(const float* __restrict__ x,
                                                    const float* __restrict__ sos,
                                                    const float* __restrict__ mats,
                                                    const float* __restrict__ zsup,
                                                    float* __restrict__ y) {
  __shared__ float Tr[WPB][64 * RST];
  const int tid = threadIdx.x, w = tid >> 6, lane = tid & 63;
  Coefs cf; load_coefs(sos, cf);
  const int S = blockIdx.x * WPB + w;
  const int r = S / NSUP, s = S - r * NSUP;
  const size_t base = (size_t)r * T_SAMP + (size_t)s * SUPW;
  const float4* src = reinterpret_cast<const float4*>(x + base + (size_t)lane * LCH);
  float4 v0 = src[0], v1 = src[1], v2 = src[2], v3 = src[3], v4 = src[4];

  float z0[6];
  const float* zp = zsup + (size_t)S * 6;
#pragma unroll
  for (int e = 0; e < 6; ++e) z0[e] = zp[e];

  // zero-state pre-pass (v kept intact)
  float f[6] = {0.f, 0.f, 0.f, 0.f, 0.f, 0.f};
  df2t_step(cf, f, v0.x); df2t_step(cf, f, v0.y); df2t_step(cf, f, v0.z); df2t_step(cf, f, v0.w);
  df2t_step(cf, f, v1.x); df2t_step(cf, f, v1.y); df2t_step(cf, f, v1.z); df2t_step(cf, f, v1.w);
  df2t_step(cf, f, v2.x); df2t_step(cf, f, v2.y); df2t_step(cf, f, v2.z); df2t_step(cf, f, v2.w);
  df2t_step(cf, f, v3.x); df2t_step(cf, f, v3.y); df2t_step(cf, f, v3.z); df2t_step(cf, f, v3.w);
  df2t_step(cf, f, v4.x); df2t_step(cf, f, v4.y); df2t_step(cf, f, v4.z); df2t_step(cf, f, v4.w);

  // fold M*z0 into lane 0's f; zero-seeded scan then yields TRUE states
  if (lane == 0) tri_combine(f, mats, z0);
#pragma unroll
  for (int k = 0; k < 6; ++k) {
    float t6[6];
#pragma unroll
    for (int e = 0; e < 6; ++e) t6[e] = __shfl_up(f[e], 1 << k);
    if (lane >= (1 << k)) tri_combine(f, mats + k * 36, t6);
  }
  float zs[6];
#pragma unroll
  for (int e = 0; e < 6; ++e) {
    float tt = __shfl_up(f[e], 1);
    zs[e] = (lane == 0) ? z0[e] : tt;
  }

  // true filter from exact chunk-start state; outputs -> LDS transpose rows
  float* myrow = &Tr[w][lane * RST];
  myrow[0]  = df2t_step(cf, zs, v0.x); myrow[1]  = df2t_step(cf, zs, v0.y);
  myrow[2]  = df2t_step(cf, zs, v0.z); myrow[3]  = df2t_step(cf, zs, v0.w);
  myrow[4]  = df2t_step(cf, zs, v1.x); myrow[5]  = df2t_step(cf, zs, v1.y);
  myrow[6]  = df2t_step(cf, zs, v1.z); myrow[7]  = df2t_step(cf, zs, v1.w);
  myrow[8]  = df2t_step(cf, zs, v2.x); myrow[9]  = df2t_step(cf, zs, v2.y);
  myrow[10] = df2t_step(cf, zs, v2.z); myrow[11] = df2t_step(cf, zs, v2.w);
  myrow[12] = df2t_step(cf, zs, v3.x); myrow[13] = df2t_step(cf, zs, v3.y);
  myrow[14] = df2t_step(cf, zs, v3.z); myrow[15] = df2t_step(cf, zs, v3.w);
  myrow[16] = df2t_step(cf, zs, v4.x); myrow[17] = df2t_step(cf, zs, v4.y);
  myrow[18] = df2t_step(cf, zs, v4.z); myrow[19] = df2t_step(cf, zs, v4.w);
  __syncthreads();

  float* dst = y + base;
#pragma unroll
  for (int i2 = 0; i2 < NF4; ++i2) {
    int q = i2 * 64 + lane, k = q / NF4, m = q - k * NF4;
    vfloat4 w4;
    w4.x = Tr[w][k * RST + m * 4 + 0];
    w4.y = Tr[w][k * RST + m * 4 + 1];
    w4.z = Tr[w][k * RST + m * 4 + 2];
    w4.w = Tr[w][k * RST + m * 4 + 3];
    __builtin_nontemporal_store(w4, reinterpret_cast<vfloat4*>(dst + 4 * q));
  }
}

extern "C" void kernel_launch(void* const* d_in, const int* in_sizes, int n_in,
                              void* d_out, int out_size, void* d_ws, size_t ws_size,
                              hipStream_t stream) {
  const float* x = (const float*)d_in[0];
  const float* sos = (const float*)d_in[1];
  float* y = (float*)d_out;

  float* Fsup = (float*)d_ws;             // [NSC][6]
  float* zsup = Fsup + (size_t)NSC * 6;   // [NSC][6]
  float* mats = zsup + (size_t)NSC * 6;   // [468]

  hipLaunchKernelGGL(setup_kernel, dim3(1), dim3(64), 0, stream, sos, mats);
  hipLaunchKernelGGL(pass1_kernel, dim3(NSC / WPB), dim3(256), 0, stream, x, sos, mats, Fsup);
  hipLaunchKernelGGL(middle_scan, dim3(B_ROWS), dim3(64), 0, stream, Fsup, mats, zsup);
  hipLaunchKernelGGL(pass2_kernel, dim3(NSC / WPB), dim3(256), 0, stream, x, sos, mats, zsup, y);
}